// Round 11
// baseline (6293.435 us; speedup 1.0000x reference)
//
#include <hip/hip_runtime.h>

// LP via PDHG. A: (4094, 16384) row-major fp32; b, c: (16384,) fp32. Out: scalar fp32.
// Round 11: round-10 structure (299 fp8 iters, two launches/iter, fp16 partials,
// fp16 final polish, POWER_ITERS=8) with:
//  - k_fused8 restructured 512x256 -> 256x512 (8 waves/block): same 2 waves/SIMD
//    occupancy, but partial round-trip 4+4 -> 2+2 MB, half the y-staging and
//    block epilogues; merge reads halve.
//  - k_scale folded into k_azp8s (scaled LDS staging): 9 fewer launches.
// fp32 fallback kept.

constexpr int N_ROWS = 4094;
constexpr int NPAD   = 4096;
constexpr int M_COLS = 16384;
constexpr int M4     = M_COLS / 4;
constexpr int PDHG_ITERS  = 300;    // 299 fp8 + 1 fp16 polish
constexpr int POWER_ITERS = 8;
constexpr int P_CHUNKS = 64;        // fp32 fallback
constexpr int ROWS_PER_CHUNK = 64;  // fp32 fallback
constexpr int FBLOCKS = 256;        // fused col-blocks (64 cols each, 8 waves)
constexpr int AZ_J  = 64;
constexpr int AZ_CH = M_COLS / AZ_J;       // 256

typedef _Float16 half8  __attribute__((ext_vector_type(8)));
typedef _Float16 half4v __attribute__((ext_vector_type(4)));
typedef _Float16 half2v __attribute__((ext_vector_type(2)));
typedef _Float16 half_t;
typedef float f32x2 __attribute__((ext_vector_type(2)));

__device__ __forceinline__ void dec8(uint2 w, float* f) {
    f32x2 a = __builtin_amdgcn_cvt_pk_f32_fp8(w.x, false);
    f32x2 b = __builtin_amdgcn_cvt_pk_f32_fp8(w.x, true);
    f32x2 c = __builtin_amdgcn_cvt_pk_f32_fp8(w.y, false);
    f32x2 d = __builtin_amdgcn_cvt_pk_f32_fp8(w.y, true);
    f[0]=a[0]; f[1]=a[1]; f[2]=b[0]; f[3]=b[1];
    f[4]=c[0]; f[5]=c[1]; f[6]=d[0]; f[7]=d[1];
}

// ---------------- init ----------------
__global__ __launch_bounds__(256) void k_init(float* __restrict__ x,
                                              float* __restrict__ v,
                                              float* __restrict__ y,
                                              float* __restrict__ t,
                                              float* __restrict__ scalars) {
    int j = blockIdx.x * 256 + threadIdx.x;
    if (j < M_COLS) { x[j] = 0.f; v[j] = 0.0078125f; }
    if (j < NPAD) { y[j] = 0.f; t[j] = 0.f; }
    if (j == 0) scalars[0] = 1.f;   // first azp8s divides by this
}

// ---------------- A -> AT8 (permuted fp8, values 64*A) AND AT16 (linear fp16) ----------------
__global__ __launch_bounds__(256) void k_transpose_both(const float* __restrict__ A,
                                                        unsigned int* __restrict__ AT8,
                                                        half_t* __restrict__ AT16) {
    __shared__ float tile[64][65];
    const int i0 = blockIdx.x * 64;   // row tile base
    const int j0 = blockIdx.y * 64;   // col tile base
    const int t = threadIdx.x;
    const float4* __restrict__ A4 = reinterpret_cast<const float4*>(A);
#pragma unroll
    for (int k = 0; k < 4; ++k) {
        int idx = k * 256 + t;
        int r = idx >> 4, c4 = idx & 15;
        int i = i0 + r;
        float4 val = (i < N_ROWS) ? A4[(size_t)i * M4 + (j0 >> 2) + c4]
                                  : make_float4(0.f, 0.f, 0.f, 0.f);
        tile[r][c4 * 4 + 0] = val.x;
        tile[r][c4 * 4 + 1] = val.y;
        tile[r][c4 * 4 + 2] = val.z;
        tile[r][c4 * 4 + 3] = val.w;
    }
    __syncthreads();
    // fp8 permuted (scaled by 64)
    const int it_p = i0 >> 9;
    const int sub  = (i0 >> 8) & 1;
    const int l0   = (i0 & 255) >> 2;
#pragma unroll
    for (int k = 0; k < 4; ++k) {
        int idx = k * 256 + t;          // 64 j x 16 lofs
        int j = idx >> 4, lofs = idx & 15;
        float f0 = tile[lofs * 4 + 0][j] * 64.f;
        float f1 = tile[lofs * 4 + 1][j] * 64.f;
        float f2 = tile[lofs * 4 + 2][j] * 64.f;
        float f3 = tile[lofs * 4 + 3][j] * 64.f;
        int r = 0;
        r = __builtin_amdgcn_cvt_pk_fp8_f32(f0, f1, r, false);
        r = __builtin_amdgcn_cvt_pk_fp8_f32(f2, f3, r, true);
        AT8[(size_t)(j0 + j) * 1024 + it_p * 128 + (l0 + lofs) * 2 + sub] = (unsigned int)r;
    }
    // fp16 linear (true values, for final polish)
    half8* __restrict__ O8 = reinterpret_cast<half8*>(AT16);
#pragma unroll
    for (int k = 0; k < 2; ++k) {
        int idx = k * 256 + t;          // 64 j x 8 q
        int j = idx >> 3, q = idx & 7;
        half8 h;
#pragma unroll
        for (int e = 0; e < 8; ++e) h[e] = (half_t)tile[q * 8 + e][j];
        O8[((size_t)(j0 + j) * NPAD + i0) / 8 + q] = h;
    }
}

// ---------------- fused PDHG x-pass + rank-1 (fp8), 512 threads, fp16 partial ----------------
__global__ __launch_bounds__(512) void k_fused8(const unsigned int* __restrict__ AT,
                                                const float* __restrict__ y,
                                                const float* __restrict__ c,
                                                const float* __restrict__ b,
                                                float* __restrict__ x,
                                                half_t* __restrict__ partial,
                                                const float* __restrict__ scalars) {
    __shared__ float ybuf[4096];      // yIn during dot phase, reused as merge buffer
    const int tid = threadIdx.x;
    const int wv = tid >> 6, lane = tid & 63;   // 8 waves
    {
        const float4* __restrict__ y4 = reinterpret_cast<const float4*>(y);
        float4* s4 = reinterpret_cast<float4*>(ybuf);
#pragma unroll
        for (int k = 0; k < 2; ++k) s4[k * 512 + tid] = y4[k * 512 + tid];
    }
    __syncthreads();
    const float tau = scalars[1];
    const int j0 = blockIdx.x * 64 + wv * 8;  // 8 cols per wave, 64 per block
    const uint2* __restrict__ A2 = reinterpret_cast<const uint2*>(AT);

    float xs = 0.f, cs = 0.f, bs = 0.f, xkeep = 0.f;
    if (lane < 8) {
        xs = x[j0 + lane];
        cs = c[j0 + lane];
        bs = b[j0 + lane];
    }

    float acc[64];
#pragma unroll
    for (int q = 0; q < 64; ++q) acc[q] = 0.f;

    uint2 cur[8], nxt[8];
#pragma unroll
    for (int p = 0; p < 8; ++p) cur[p] = A2[(size_t)j0 * 512 + p * 64 + lane];

    for (int q = 0; q < 8; ++q) {
        const int j = j0 + q;
        if (q + 1 < 8) {
#pragma unroll
            for (int p = 0; p < 8; ++p) nxt[p] = A2[(size_t)(j + 1) * 512 + p * 64 + lane];
        }
        float s = 0.f;
#pragma unroll
        for (int p = 0; p < 8; ++p) {
            float f[8];
            dec8(cur[p], f);
            const float4 ya = *reinterpret_cast<const float4*>(&ybuf[p * 512 + lane * 4]);
            const float4 yb = *reinterpret_cast<const float4*>(&ybuf[p * 512 + 256 + lane * 4]);
            s = fmaf(f[0], ya.x, s);
            s = fmaf(f[1], ya.y, s);
            s = fmaf(f[2], ya.z, s);
            s = fmaf(f[3], ya.w, s);
            s = fmaf(f[4], yb.x, s);
            s = fmaf(f[5], yb.y, s);
            s = fmaf(f[6], yb.z, s);
            s = fmaf(f[7], yb.w, s);
        }
#pragma unroll
        for (int o = 1; o < 64; o <<= 1) s += __shfl_xor(s, o, 64);
        s *= 0.015625f;                       // /64: values were 64*A
        float xo = __shfl(xs, q, 64);
        float cj = __shfl(cs, q, 64);
        float bj = __shfl(bs, q, 64);
        float xn = xo - tau * (cj + s);
        xn = fminf(fmaxf(xn, 0.f), bj);
        if (lane == q) xkeep = xn;
        float z = 2.f * xn - xo;
#pragma unroll
        for (int p = 0; p < 8; ++p) {
            float f[8];
            dec8(cur[p], f);
#pragma unroll
            for (int e = 0; e < 8; ++e)
                acc[p * 8 + e] = fmaf(f[e], z, acc[p * 8 + e]);
        }
#pragma unroll
        for (int p = 0; p < 8; ++p) cur[p] = nxt[p];
    }
    if (lane < 8) x[j0 + lane] = xkeep;

    __syncthreads();   // all waves done reading ybuf; safe to overwrite
    for (int w = 0; w < 8; ++w) {
        if (wv == w) {
#pragma unroll
            for (int p = 0; p < 8; ++p) {
                float4* pa = reinterpret_cast<float4*>(&ybuf[p * 512 + lane * 4]);
                float4* pb = reinterpret_cast<float4*>(&ybuf[p * 512 + 256 + lane * 4]);
                float4 va = make_float4(acc[p * 8 + 0], acc[p * 8 + 1], acc[p * 8 + 2], acc[p * 8 + 3]);
                float4 vb = make_float4(acc[p * 8 + 4], acc[p * 8 + 5], acc[p * 8 + 6], acc[p * 8 + 7]);
                if (w == 0) { *pa = va; *pb = vb; }
                else {
                    float4 oa = *pa, ob = *pb;
                    oa.x += va.x; oa.y += va.y; oa.z += va.z; oa.w += va.w;
                    ob.x += vb.x; ob.y += vb.y; ob.z += vb.z; ob.w += vb.w;
                    *pa = oa; *pb = ob;
                }
            }
        }
        __syncthreads();
    }
    // fp16 partial write (logical row order)
    half_t* __restrict__ ph = partial + (size_t)blockIdx.x * 4096;
    const float4* __restrict__ S4 = reinterpret_cast<const float4*>(ybuf);
#pragma unroll
    for (int k = 0; k < 2; ++k) {
        float4 vv = S4[k * 512 + tid];
        half4v h;
        h[0] = (half_t)vv.x; h[1] = (half_t)vv.y; h[2] = (half_t)vv.z; h[3] = (half_t)vv.w;
        *reinterpret_cast<half4v*>(&ph[k * 2048 + tid * 4]) = h;
    }
}

// ---------------- fp16 partial merge: y[row] += scalars[2] * sum_p partial[p][row] ----------------
template <int NP>
__global__ __launch_bounds__(256) void k_merge_h(const half_t* __restrict__ partial,
                                                 float* __restrict__ y,
                                                 const float* __restrict__ scalars) {
    __shared__ float2 smf[256];
    const int tid = threadIdx.x;
    const int mb = blockIdx.x;                // 0..255, owns rows [mb*16, mb*16+16)
    const int rp = tid & 7;                   // row-pair within the 16-row group
    const int kk = tid >> 3;                  // 0..31 partial-groups of NP/32
    const half2v* __restrict__ ph2 = reinterpret_cast<const half2v*>(partial);
    float sx = 0.f, sy = 0.f;
#pragma unroll
    for (int q = 0; q < NP / 32; ++q) {
        int p = kk * (NP / 32) + q;
        half2v h = ph2[(size_t)p * 2048 + mb * 8 + rp];
        sx += (float)h[0];
        sy += (float)h[1];
    }
    smf[kk * 8 + rp] = make_float2(sx, sy);
    __syncthreads();
    if (tid < 16) {
        int pairIdx = tid >> 1, comp = tid & 1;
        float tot = 0.f;
#pragma unroll
        for (int k2 = 0; k2 < 32; ++k2) {
            float2 f2 = smf[k2 * 8 + pairIdx];
            tot += comp ? f2.y : f2.x;
        }
        y[mb * 16 + tid] += scalars[2] * tot;   // scalars[2] = tau/64
    }
}

// ---------------- power-iter partial merge (fp32): out = sum_p partial[p][row] ----------------
template <int NP>
__global__ __launch_bounds__(256) void k_merge0(const float* __restrict__ partial,
                                                float* __restrict__ out) {
    constexpr int PER = NP / 16;
    const int tid = threadIdx.x;
    const int r = tid & 15, k = tid >> 4;
    const int row = blockIdx.x * 16 + r;
    const float* __restrict__ p0 = partial + (size_t)k * PER * NPAD + row;
    float s = 0.f;
#pragma unroll 8
    for (int q = 0; q < PER; ++q) s += p0[(size_t)q * NPAD];
    __shared__ float sm[256];
    sm[tid] = s;
    __syncthreads();
    if (tid < 16) {
        const int orow = blockIdx.x * 16 + tid;
        float tot = 0.f;
#pragma unroll
        for (int kk = 0; kk < 16; ++kk) tot += sm[kk * 16 + tid];
        out[orow] = tot;
    }
}

// ---------------- power iter: w[j] = <AT8_j, u> (raw scaled) ----------------
__global__ __launch_bounds__(256) void k_colp8(const unsigned int* __restrict__ AT,
                                               const float* __restrict__ u,
                                               float* __restrict__ w) {
    const int wv = threadIdx.x >> 6, lane = threadIdx.x & 63;
    const int j = blockIdx.x * 4 + wv;
    const uint2* __restrict__ A2 = reinterpret_cast<const uint2*>(AT);
    const float4* __restrict__ u4 = reinterpret_cast<const float4*>(u);
    float s = 0.f;
#pragma unroll
    for (int p = 0; p < 8; ++p) {
        float f[8];
        dec8(A2[(size_t)j * 512 + p * 64 + lane], f);
        float4 ua = u4[p * 128 + lane];
        float4 ub = u4[p * 128 + 64 + lane];
        s = fmaf(f[0], ua.x, s);
        s = fmaf(f[1], ua.y, s);
        s = fmaf(f[2], ua.z, s);
        s = fmaf(f[3], ua.w, s);
        s = fmaf(f[4], ub.x, s);
        s = fmaf(f[5], ub.y, s);
        s = fmaf(f[6], ub.z, s);
        s = fmaf(f[7], ub.w, s);
    }
#pragma unroll
    for (int o = 1; o < 64; o <<= 1) s += __shfl_xor(s, o, 64);
    if (lane == 0) w[j] = s;
}

// ---------------- power iter: partial[ch][i] = sum_{j in ch} AT8[j][i] * (zv[j]/scalars[0]) ----
__global__ __launch_bounds__(256) void k_azp8s(const unsigned int* __restrict__ AT,
                                               const float* __restrict__ zv,
                                               float* __restrict__ partial,
                                               const float* __restrict__ scalars) {
    const int ch = blockIdx.y;
    const int j0 = ch * AZ_J;
    const int p = blockIdx.x * 256 + threadIdx.x;   // phys uint2 idx 0..511
    __shared__ float sz[AZ_J];
    if (threadIdx.x < AZ_J) sz[threadIdx.x] = zv[j0 + threadIdx.x] / scalars[0];
    __syncthreads();
    const uint2* __restrict__ A2 = reinterpret_cast<const uint2*>(AT);
    float acc[8];
#pragma unroll
    for (int e = 0; e < 8; ++e) acc[e] = 0.f;
    for (int jj = 0; jj < AZ_J; ++jj) {
        float f[8];
        dec8(A2[(size_t)(j0 + jj) * 512 + p], f);
        float zj = sz[jj];
#pragma unroll
        for (int e = 0; e < 8; ++e) acc[e] = fmaf(f[e], zj, acc[e]);
    }
    const int ibase = (p >> 6) * 512 + (p & 63) * 4;
    float* __restrict__ P = partial + (size_t)ch * NPAD;
    *reinterpret_cast<float4*>(&P[ibase])       = make_float4(acc[0], acc[1], acc[2], acc[3]);
    *reinterpret_cast<float4*>(&P[ibase + 256]) = make_float4(acc[4], acc[5], acc[6], acc[7]);
}

// ---------------- final polish: fp16 column dot + x-update ----------------
template <int MODE>
__global__ __launch_bounds__(256) void k_col(const half_t* __restrict__ AT,
                                             const float* __restrict__ u,
                                             const float* __restrict__ c,
                                             const float* __restrict__ b,
                                             float* __restrict__ x,
                                             float* __restrict__ z,
                                             float* __restrict__ w,
                                             const float* __restrict__ scalars) {
    const int wv   = threadIdx.x >> 6;
    const int lane = threadIdx.x & 63;
    const int j = blockIdx.x * 4 + wv;
    const half8* __restrict__ row = reinterpret_cast<const half8*>(AT + (size_t)j * NPAD);
    const float4* __restrict__ u4 = reinterpret_cast<const float4*>(u);
    float s = 0.f;
#pragma unroll
    for (int it = 0; it < NPAD / 8 / 64; ++it) {
        int k = it * 64 + lane;
        half8 a = row[k];
        float4 ua = u4[2 * k];
        float4 ub = u4[2 * k + 1];
        s = fmaf((float)a[0], ua.x, s);
        s = fmaf((float)a[1], ua.y, s);
        s = fmaf((float)a[2], ua.z, s);
        s = fmaf((float)a[3], ua.w, s);
        s = fmaf((float)a[4], ub.x, s);
        s = fmaf((float)a[5], ub.y, s);
        s = fmaf((float)a[6], ub.z, s);
        s = fmaf((float)a[7], ub.w, s);
    }
#pragma unroll
    for (int o = 1; o < 64; o <<= 1) s += __shfl_xor(s, o, 64);
    if (lane == 0) {
        if (MODE == 0) {
            w[j] = s;
        } else {
            float tau = scalars[1];
            float xo = x[j];
            float xn = xo - tau * (c[j] + s);
            xn = fminf(fmaxf(xn, 0.f), b[j]);
            x[j] = xn;
            z[j] = 2.f * xn - xo;
        }
    }
}

// ================= fp32 fallback kernels (round-1 verified) =================
__global__ __launch_bounds__(256) void k_at_partial(const float* __restrict__ A,
                                                    const float* __restrict__ u,
                                                    float* __restrict__ partial) {
    const int j4 = blockIdx.x * 256 + threadIdx.x;
    const int r0 = blockIdx.y * ROWS_PER_CHUNK;
    const int r1 = min(r0 + ROWS_PER_CHUNK, N_ROWS);
    __shared__ float su[ROWS_PER_CHUNK];
    if (threadIdx.x < (unsigned)(r1 - r0)) su[threadIdx.x] = u[r0 + threadIdx.x];
    __syncthreads();
    const float4* __restrict__ A4 = reinterpret_cast<const float4*>(A);
    float4 acc = make_float4(0.f, 0.f, 0.f, 0.f);
    for (int i = r0; i < r1; ++i) {
        const float ui = su[i - r0];
        float4 a = A4[(size_t)i * M4 + j4];
        acc.x = fmaf(a.x, ui, acc.x);
        acc.y = fmaf(a.y, ui, acc.y);
        acc.z = fmaf(a.z, ui, acc.z);
        acc.w = fmaf(a.w, ui, acc.w);
    }
    reinterpret_cast<float4*>(partial)[(size_t)blockIdx.y * M4 + j4] = acc;
}

__global__ __launch_bounds__(256) void k_reduce_w(const float* __restrict__ partial,
                                                  float* __restrict__ w) {
    int j = blockIdx.x * 256 + threadIdx.x;
    float s = 0.f;
    for (int p = 0; p < P_CHUNKS; ++p) s += partial[(size_t)p * M_COLS + j];
    w[j] = s;
}

__global__ __launch_bounds__(256) void k_x_update(const float* __restrict__ partial,
                                                  const float* __restrict__ c,
                                                  const float* __restrict__ b,
                                                  float* __restrict__ x,
                                                  float* __restrict__ z,
                                                  const float* __restrict__ scalars) {
    int j = blockIdx.x * 256 + threadIdx.x;
    const float tau = scalars[1];
    float s = 0.f;
    for (int p = 0; p < P_CHUNKS; ++p) s += partial[(size_t)p * M_COLS + j];
    float xo = x[j];
    float xn = xo - tau * (c[j] + s);
    xn = fminf(fmaxf(xn, 0.f), b[j]);
    x[j] = xn;
    z[j] = 2.f * xn - xo;
}

template <int MODE>
__global__ __launch_bounds__(256) void k_row_dot(const float* __restrict__ A,
                                                 const float* __restrict__ vec,
                                                 float* __restrict__ out,
                                                 const float* __restrict__ scalars) {
    const int i = blockIdx.x;
    const float4* __restrict__ row = reinterpret_cast<const float4*>(A + (size_t)i * M_COLS);
    const float4* __restrict__ v4  = reinterpret_cast<const float4*>(vec);
    float s = 0.f;
    for (int k = threadIdx.x; k < M4; k += 256) {
        float4 a = row[k];
        float4 v = v4[k];
        s = fmaf(a.x, v.x, s);
        s = fmaf(a.y, v.y, s);
        s = fmaf(a.z, v.z, s);
        s = fmaf(a.w, v.w, s);
    }
    for (int o = 32; o > 0; o >>= 1) s += __shfl_down(s, o, 64);
    __shared__ float sm[4];
    if ((threadIdx.x & 63) == 0) sm[threadIdx.x >> 6] = s;
    __syncthreads();
    if (threadIdx.x == 0) {
        float t = sm[0] + sm[1] + sm[2] + sm[3];
        if (MODE == 0) out[i] = t;
        else           out[i] += scalars[1] * t;
    }
}

// ---------------- norms ----------------
// MODE 0: scalars[0] = ||w||
// MODE 1: fp8-scaled: w = 4096*A^T A v -> tau = 57.6/sqrt(||w||); scalars[2]=tau/64
// MODE 2: true-scale: tau = 0.9/sqrt(||w||)
template <int MODE>
__global__ __launch_bounds__(1024) void k_norm(const float* __restrict__ w,
                                               float* __restrict__ scalars) {
    const float4* __restrict__ w4 = reinterpret_cast<const float4*>(w);
    float s = 0.f;
    for (int k = threadIdx.x; k < M4; k += 1024) {
        float4 a = w4[k];
        s = fmaf(a.x, a.x, s);
        s = fmaf(a.y, a.y, s);
        s = fmaf(a.z, a.z, s);
        s = fmaf(a.w, a.w, s);
    }
    for (int o = 32; o > 0; o >>= 1) s += __shfl_down(s, o, 64);
    __shared__ float sm[16];
    if ((threadIdx.x & 63) == 0) sm[threadIdx.x >> 6] = s;
    __syncthreads();
    if (threadIdx.x == 0) {
        float t = 0.f;
        for (int q = 0; q < 16; ++q) t += sm[q];
        float nrm = sqrtf(t);               // ||w||
        if (MODE == 0) scalars[0] = nrm;
        else if (MODE == 1) {
            float tau = 57.6f / sqrtf(nrm); // 0.9*64/sqrt(||w||_meas)
            scalars[1] = tau;
            scalars[2] = tau * 0.015625f;
        } else {
            scalars[1] = 0.9f / sqrtf(nrm);
        }
    }
}

__global__ __launch_bounds__(256) void k_scale(const float* __restrict__ w,
                                               float* __restrict__ v,
                                               const float* __restrict__ scalars) {
    int j = blockIdx.x * 256 + threadIdx.x;
    v[j] = w[j] / scalars[0];
}

__global__ __launch_bounds__(1024) void k_obj(const float* __restrict__ x,
                                              const float* __restrict__ c,
                                              float* __restrict__ out) {
    float s = 0.f;
    for (int k = threadIdx.x; k < M_COLS; k += 1024) s = fmaf(x[k], -c[k], s);
    for (int o = 32; o > 0; o >>= 1) s += __shfl_down(s, o, 64);
    __shared__ float sm[16];
    if ((threadIdx.x & 63) == 0) sm[threadIdx.x >> 6] = s;
    __syncthreads();
    if (threadIdx.x == 0) {
        float t = 0.f;
        for (int q = 0; q < 16; ++q) t += sm[q];
        out[0] = t;
    }
}

extern "C" void kernel_launch(void* const* d_in, const int* in_sizes, int n_in,
                              void* d_out, int out_size, void* d_ws, size_t ws_size,
                              hipStream_t stream) {
    const float* A = (const float*)d_in[0];
    const float* b = (const float*)d_in[1];
    const float* c = (const float*)d_in[2];
    float* out = (float*)d_out;

    float* ws = (float*)d_ws;
    float* x       = ws;                        // M
    float* z       = x + M_COLS;                // M
    float* v       = z + M_COLS;                // M
    float* w       = v + M_COLS;                // M
    float* y       = w + M_COLS;                // NPAD
    float* t       = y + NPAD;                  // NPAD
    float* scalars = t + NPAD;                  // 16
    float* partial = scalars + 16;              // 8 MB region (fp32 power / fp16 PDHG)

    size_t partial_floats = (size_t)2 * 1024 * 1024;
    size_t base = (size_t)(partial - ws) * 4 + partial_floats * 4;
    size_t a8_off = (base + 255) & ~(size_t)255;
    unsigned int* AT8 = (unsigned int*)((char*)d_ws + a8_off);
    size_t a8_bytes = (size_t)M_COLS * NPAD;                  // 64 MB
    size_t a16_off = (a8_off + a8_bytes + 255) & ~(size_t)255;
    half_t* AT16 = (half_t*)((char*)d_ws + a16_off);
    size_t a16_bytes = (size_t)M_COLS * NPAD * sizeof(half_t); // 134.2 MB
    size_t need_full = a16_off + a16_bytes;                    // ~207 MB
    size_t need_fp32 = (size_t)(partial - ws) * 4 + (size_t)P_CHUNKS * M_COLS * 4;

    dim3 b256(256);
    dim3 b512(512);
    dim3 gM(M_COLS / 256);            // 64
    dim3 gCol(M_COLS / 4);            // 4096
    dim3 gFused(FBLOCKS);             // 256 blocks x 512 threads
    dim3 gAz(NPAD / 8 / 256, AZ_CH);  // (2, 256)
    dim3 gMerge(NPAD / 16);           // 256
    dim3 gRowA(N_ROWS);
    dim3 gTr(NPAD / 64, M_COLS / 64); // (64, 256)

    k_init<<<gM, b256, 0, stream>>>(x, v, y, t, scalars);

    if (ws_size >= need_full) {
        // ======== fp8 path: 299 two-launch iters + fp16 polish ========
        k_transpose_both<<<gTr, b256, 0, stream>>>(A, AT8, AT16);

        // power iteration with scaled staging (no explicit normalize kernel)
        k_azp8s<<<gAz, b256, 0, stream>>>(AT8, v, partial, scalars);   // v/1
        k_merge0<AZ_CH><<<gMerge, b256, 0, stream>>>(partial, t);
        k_colp8<<<gCol, b256, 0, stream>>>(AT8, t, w);
        k_norm<0><<<1, 1024, 0, stream>>>(w, scalars);
        for (int it = 1; it < POWER_ITERS; ++it) {
            k_azp8s<<<gAz, b256, 0, stream>>>(AT8, w, partial, scalars); // w/||w||
            k_merge0<AZ_CH><<<gMerge, b256, 0, stream>>>(partial, t);
            k_colp8<<<gCol, b256, 0, stream>>>(AT8, t, w);
            k_norm<0><<<1, 1024, 0, stream>>>(w, scalars);
        }
        k_azp8s<<<gAz, b256, 0, stream>>>(AT8, w, partial, scalars);
        k_merge0<AZ_CH><<<gMerge, b256, 0, stream>>>(partial, t);
        k_colp8<<<gCol, b256, 0, stream>>>(AT8, t, w);
        k_norm<1><<<1, 1024, 0, stream>>>(w, scalars);                 // tau, tau/64

        for (int it = 0; it < PDHG_ITERS - 1; ++it) {
            k_fused8<<<gFused, b512, 0, stream>>>(AT8, y, c, b, x,
                                                  (half_t*)partial, scalars);
            k_merge_h<FBLOCKS><<<gMerge, b256, 0, stream>>>((half_t*)partial, y, scalars);
        }
        // final x-step (its y-half is unused by the output) in fp16
        k_col<1><<<gCol, b256, 0, stream>>>(AT16, y, c, b, x, z, w, scalars);
    } else if (ws_size >= need_fp32) {
        // ======== fp32 fallback (full 300, 20 power iters) ========
        dim3 gAt(M4 / 256, P_CHUNKS);
        for (int it = 0; it < 20; ++it) {
            k_row_dot<0><<<gRowA, b256, 0, stream>>>(A, v, t, scalars);
            k_at_partial<<<gAt, b256, 0, stream>>>(A, t, partial);
            k_reduce_w<<<gM, b256, 0, stream>>>(partial, w);
            k_norm<0><<<1, 1024, 0, stream>>>(w, scalars);
            k_scale<<<gM, b256, 0, stream>>>(w, v, scalars);
        }
        k_row_dot<0><<<gRowA, b256, 0, stream>>>(A, v, t, scalars);
        k_at_partial<<<gAt, b256, 0, stream>>>(A, t, partial);
        k_reduce_w<<<gM, b256, 0, stream>>>(partial, w);
        k_norm<2><<<1, 1024, 0, stream>>>(w, scalars);
        for (int it = 0; it < PDHG_ITERS; ++it) {
            k_at_partial<<<gAt, b256, 0, stream>>>(A, y, partial);
            k_x_update<<<gM, b256, 0, stream>>>(partial, c, b, x, z, scalars);
            k_row_dot<1><<<gRowA, b256, 0, stream>>>(A, z, y, scalars);
        }
    }

    k_obj<<<1, 1024, 0, stream>>>(x, c, out);
}

// Round 12
// 5842.805 us; speedup vs baseline: 1.0771x; 1.0771x over previous
//
#include <hip/hip_runtime.h>

// LP via PDHG. A: (4094, 16384) row-major fp32; b, c: (16384,) fp32. Out: scalar fp32.
// Round 12: round-11 structure (299 fp8 iters, 256x512 fused + merge launch/iter,
// fp16 partials, fp16 final polish, POWER_ITERS=8, fused transpose) with the
// k_fused8 epilogue restructured: 8-step serial wave merge -> 3-level parallel
// tree in 64 KB LDS; wave 0 writes the fp16 partial directly from registers.
// fp32 fallback kept.

constexpr int N_ROWS = 4094;
constexpr int NPAD   = 4096;
constexpr int M_COLS = 16384;
constexpr int M4     = M_COLS / 4;
constexpr int PDHG_ITERS  = 300;    // 299 fp8 + 1 fp16 polish
constexpr int POWER_ITERS = 8;
constexpr int P_CHUNKS = 64;        // fp32 fallback
constexpr int ROWS_PER_CHUNK = 64;  // fp32 fallback
constexpr int FBLOCKS = 256;        // fused col-blocks (64 cols each, 8 waves)
constexpr int AZ_J  = 64;
constexpr int AZ_CH = M_COLS / AZ_J;       // 256

typedef _Float16 half8  __attribute__((ext_vector_type(8)));
typedef _Float16 half4v __attribute__((ext_vector_type(4)));
typedef _Float16 half2v __attribute__((ext_vector_type(2)));
typedef _Float16 half_t;
typedef float f32x2 __attribute__((ext_vector_type(2)));

__device__ __forceinline__ void dec8(uint2 w, float* f) {
    f32x2 a = __builtin_amdgcn_cvt_pk_f32_fp8(w.x, false);
    f32x2 b = __builtin_amdgcn_cvt_pk_f32_fp8(w.x, true);
    f32x2 c = __builtin_amdgcn_cvt_pk_f32_fp8(w.y, false);
    f32x2 d = __builtin_amdgcn_cvt_pk_f32_fp8(w.y, true);
    f[0]=a[0]; f[1]=a[1]; f[2]=b[0]; f[3]=b[1];
    f[4]=c[0]; f[5]=c[1]; f[6]=d[0]; f[7]=d[1];
}

// ---------------- init ----------------
__global__ __launch_bounds__(256) void k_init(float* __restrict__ x,
                                              float* __restrict__ v,
                                              float* __restrict__ y,
                                              float* __restrict__ t,
                                              float* __restrict__ scalars) {
    int j = blockIdx.x * 256 + threadIdx.x;
    if (j < M_COLS) { x[j] = 0.f; v[j] = 0.0078125f; }
    if (j < NPAD) { y[j] = 0.f; t[j] = 0.f; }
    if (j == 0) scalars[0] = 1.f;   // first azp8s divides by this
}

// ---------------- A -> AT8 (permuted fp8, values 64*A) AND AT16 (linear fp16) ----------------
__global__ __launch_bounds__(256) void k_transpose_both(const float* __restrict__ A,
                                                        unsigned int* __restrict__ AT8,
                                                        half_t* __restrict__ AT16) {
    __shared__ float tile[64][65];
    const int i0 = blockIdx.x * 64;   // row tile base
    const int j0 = blockIdx.y * 64;   // col tile base
    const int t = threadIdx.x;
    const float4* __restrict__ A4 = reinterpret_cast<const float4*>(A);
#pragma unroll
    for (int k = 0; k < 4; ++k) {
        int idx = k * 256 + t;
        int r = idx >> 4, c4 = idx & 15;
        int i = i0 + r;
        float4 val = (i < N_ROWS) ? A4[(size_t)i * M4 + (j0 >> 2) + c4]
                                  : make_float4(0.f, 0.f, 0.f, 0.f);
        tile[r][c4 * 4 + 0] = val.x;
        tile[r][c4 * 4 + 1] = val.y;
        tile[r][c4 * 4 + 2] = val.z;
        tile[r][c4 * 4 + 3] = val.w;
    }
    __syncthreads();
    // fp8 permuted (scaled by 64)
    const int it_p = i0 >> 9;
    const int sub  = (i0 >> 8) & 1;
    const int l0   = (i0 & 255) >> 2;
#pragma unroll
    for (int k = 0; k < 4; ++k) {
        int idx = k * 256 + t;          // 64 j x 16 lofs
        int j = idx >> 4, lofs = idx & 15;
        float f0 = tile[lofs * 4 + 0][j] * 64.f;
        float f1 = tile[lofs * 4 + 1][j] * 64.f;
        float f2 = tile[lofs * 4 + 2][j] * 64.f;
        float f3 = tile[lofs * 4 + 3][j] * 64.f;
        int r = 0;
        r = __builtin_amdgcn_cvt_pk_fp8_f32(f0, f1, r, false);
        r = __builtin_amdgcn_cvt_pk_fp8_f32(f2, f3, r, true);
        AT8[(size_t)(j0 + j) * 1024 + it_p * 128 + (l0 + lofs) * 2 + sub] = (unsigned int)r;
    }
    // fp16 linear (true values, for final polish)
    half8* __restrict__ O8 = reinterpret_cast<half8*>(AT16);
#pragma unroll
    for (int k = 0; k < 2; ++k) {
        int idx = k * 256 + t;          // 64 j x 8 q
        int j = idx >> 3, q = idx & 7;
        half8 h;
#pragma unroll
        for (int e = 0; e < 8; ++e) h[e] = (half_t)tile[q * 8 + e][j];
        O8[((size_t)(j0 + j) * NPAD + i0) / 8 + q] = h;
    }
}

// ---- LDS region helpers for the tree merge (region = float[4096], layout p*512+sub*256+lane*4+e)
__device__ __forceinline__ void reg_write(float* __restrict__ R, const float* acc, int lane) {
#pragma unroll
    for (int p = 0; p < 8; ++p) {
        *reinterpret_cast<float4*>(&R[p * 512 + lane * 4]) =
            make_float4(acc[p * 8 + 0], acc[p * 8 + 1], acc[p * 8 + 2], acc[p * 8 + 3]);
        *reinterpret_cast<float4*>(&R[p * 512 + 256 + lane * 4]) =
            make_float4(acc[p * 8 + 4], acc[p * 8 + 5], acc[p * 8 + 6], acc[p * 8 + 7]);
    }
}
__device__ __forceinline__ void reg_add(const float* __restrict__ R, float* acc, int lane) {
#pragma unroll
    for (int p = 0; p < 8; ++p) {
        float4 a = *reinterpret_cast<const float4*>(&R[p * 512 + lane * 4]);
        float4 b = *reinterpret_cast<const float4*>(&R[p * 512 + 256 + lane * 4]);
        acc[p * 8 + 0] += a.x; acc[p * 8 + 1] += a.y;
        acc[p * 8 + 2] += a.z; acc[p * 8 + 3] += a.w;
        acc[p * 8 + 4] += b.x; acc[p * 8 + 5] += b.y;
        acc[p * 8 + 6] += b.z; acc[p * 8 + 7] += b.w;
    }
}

// ---------------- fused PDHG x-pass + rank-1 (fp8), 512 threads, tree epilogue ----------------
__global__ __launch_bounds__(512) void k_fused8(const unsigned int* __restrict__ AT,
                                                const float* __restrict__ y,
                                                const float* __restrict__ c,
                                                const float* __restrict__ b,
                                                float* __restrict__ x,
                                                half_t* __restrict__ partial,
                                                const float* __restrict__ scalars) {
    __shared__ float ybuf[4096];      // yIn during dot phase; tree region 0 after
    __shared__ float scr[3][4096];    // tree regions 1..3
    const int tid = threadIdx.x;
    const int wv = tid >> 6, lane = tid & 63;   // 8 waves
    {
        const float4* __restrict__ y4 = reinterpret_cast<const float4*>(y);
        float4* s4 = reinterpret_cast<float4*>(ybuf);
#pragma unroll
        for (int k = 0; k < 2; ++k) s4[k * 512 + tid] = y4[k * 512 + tid];
    }
    __syncthreads();
    const float tau = scalars[1];
    const int j0 = blockIdx.x * 64 + wv * 8;  // 8 cols per wave, 64 per block
    const uint2* __restrict__ A2 = reinterpret_cast<const uint2*>(AT);

    float xs = 0.f, cs = 0.f, bs = 0.f, xkeep = 0.f;
    if (lane < 8) {
        xs = x[j0 + lane];
        cs = c[j0 + lane];
        bs = b[j0 + lane];
    }

    float acc[64];
#pragma unroll
    for (int q = 0; q < 64; ++q) acc[q] = 0.f;

    uint2 cur[8], nxt[8];
#pragma unroll
    for (int p = 0; p < 8; ++p) cur[p] = A2[(size_t)j0 * 512 + p * 64 + lane];

    for (int q = 0; q < 8; ++q) {
        const int j = j0 + q;
        if (q + 1 < 8) {
#pragma unroll
            for (int p = 0; p < 8; ++p) nxt[p] = A2[(size_t)(j + 1) * 512 + p * 64 + lane];
        }
        float s = 0.f;
#pragma unroll
        for (int p = 0; p < 8; ++p) {
            float f[8];
            dec8(cur[p], f);
            const float4 ya = *reinterpret_cast<const float4*>(&ybuf[p * 512 + lane * 4]);
            const float4 yb = *reinterpret_cast<const float4*>(&ybuf[p * 512 + 256 + lane * 4]);
            s = fmaf(f[0], ya.x, s);
            s = fmaf(f[1], ya.y, s);
            s = fmaf(f[2], ya.z, s);
            s = fmaf(f[3], ya.w, s);
            s = fmaf(f[4], yb.x, s);
            s = fmaf(f[5], yb.y, s);
            s = fmaf(f[6], yb.z, s);
            s = fmaf(f[7], yb.w, s);
        }
#pragma unroll
        for (int o = 1; o < 64; o <<= 1) s += __shfl_xor(s, o, 64);
        s *= 0.015625f;                       // /64: values were 64*A
        float xo = __shfl(xs, q, 64);
        float cj = __shfl(cs, q, 64);
        float bj = __shfl(bs, q, 64);
        float xn = xo - tau * (cj + s);
        xn = fminf(fmaxf(xn, 0.f), bj);
        if (lane == q) xkeep = xn;
        float z = 2.f * xn - xo;
#pragma unroll
        for (int p = 0; p < 8; ++p) {
            float f[8];
            dec8(cur[p], f);
#pragma unroll
            for (int e = 0; e < 8; ++e)
                acc[p * 8 + e] = fmaf(f[e], z, acc[p * 8 + e]);
        }
#pragma unroll
        for (int p = 0; p < 8; ++p) cur[p] = nxt[p];
    }
    if (lane < 8) x[j0 + lane] = xkeep;

    __syncthreads();   // all waves done reading ybuf; tree may overwrite it
    // ---- 3-level parallel tree merge: 8 -> 4 -> 2 -> 1 (wave 0 holds total) ----
    // Level 1: waves 4..7 publish; waves 0..3 add.
    if (wv >= 4) reg_write(wv == 4 ? ybuf : scr[wv - 5], acc, lane);
    __syncthreads();
    if (wv < 4) reg_add(wv == 0 ? ybuf : scr[wv - 1], acc, lane);
    __syncthreads();
    // Level 2: waves 2,3 publish; waves 0,1 add.
    if (wv == 2) reg_write(ybuf, acc, lane);
    if (wv == 3) reg_write(scr[0], acc, lane);
    __syncthreads();
    if (wv == 0) reg_add(ybuf, acc, lane);
    if (wv == 1) reg_add(scr[0], acc, lane);
    __syncthreads();
    // Level 3: wave 1 publishes; wave 0 adds and writes fp16 partial from registers.
    if (wv == 1) reg_write(ybuf, acc, lane);
    __syncthreads();
    if (wv == 0) {
        reg_add(ybuf, acc, lane);
        half_t* __restrict__ ph = partial + (size_t)blockIdx.x * 4096;
#pragma unroll
        for (int p = 0; p < 8; ++p) {
            half4v h0, h1;
            h0[0] = (half_t)acc[p * 8 + 0]; h0[1] = (half_t)acc[p * 8 + 1];
            h0[2] = (half_t)acc[p * 8 + 2]; h0[3] = (half_t)acc[p * 8 + 3];
            h1[0] = (half_t)acc[p * 8 + 4]; h1[1] = (half_t)acc[p * 8 + 5];
            h1[2] = (half_t)acc[p * 8 + 6]; h1[3] = (half_t)acc[p * 8 + 7];
            *reinterpret_cast<half4v*>(&ph[p * 512 + lane * 4])       = h0;
            *reinterpret_cast<half4v*>(&ph[p * 512 + 256 + lane * 4]) = h1;
        }
    }
}

// ---------------- fp16 partial merge: y[row] += scalars[2] * sum_p partial[p][row] ----------------
template <int NP>
__global__ __launch_bounds__(256) void k_merge_h(const half_t* __restrict__ partial,
                                                 float* __restrict__ y,
                                                 const float* __restrict__ scalars) {
    __shared__ float2 smf[256];
    const int tid = threadIdx.x;
    const int mb = blockIdx.x;                // 0..255, owns rows [mb*16, mb*16+16)
    const int rp = tid & 7;                   // row-pair within the 16-row group
    const int kk = tid >> 3;                  // 0..31 partial-groups of NP/32
    const half2v* __restrict__ ph2 = reinterpret_cast<const half2v*>(partial);
    float sx = 0.f, sy = 0.f;
#pragma unroll
    for (int q = 0; q < NP / 32; ++q) {
        int p = kk * (NP / 32) + q;
        half2v h = ph2[(size_t)p * 2048 + mb * 8 + rp];
        sx += (float)h[0];
        sy += (float)h[1];
    }
    smf[kk * 8 + rp] = make_float2(sx, sy);
    __syncthreads();
    if (tid < 16) {
        int pairIdx = tid >> 1, comp = tid & 1;
        float tot = 0.f;
#pragma unroll
        for (int k2 = 0; k2 < 32; ++k2) {
            float2 f2 = smf[k2 * 8 + pairIdx];
            tot += comp ? f2.y : f2.x;
        }
        y[mb * 16 + tid] += scalars[2] * tot;   // scalars[2] = tau/64
    }
}

// ---------------- power-iter partial merge (fp32): out = sum_p partial[p][row] ----------------
template <int NP>
__global__ __launch_bounds__(256) void k_merge0(const float* __restrict__ partial,
                                                float* __restrict__ out) {
    constexpr int PER = NP / 16;
    const int tid = threadIdx.x;
    const int r = tid & 15, k = tid >> 4;
    const int row = blockIdx.x * 16 + r;
    const float* __restrict__ p0 = partial + (size_t)k * PER * NPAD + row;
    float s = 0.f;
#pragma unroll 8
    for (int q = 0; q < PER; ++q) s += p0[(size_t)q * NPAD];
    __shared__ float sm[256];
    sm[tid] = s;
    __syncthreads();
    if (tid < 16) {
        const int orow = blockIdx.x * 16 + tid;
        float tot = 0.f;
#pragma unroll
        for (int kk = 0; kk < 16; ++kk) tot += sm[kk * 16 + tid];
        out[orow] = tot;
    }
}

// ---------------- power iter: w[j] = <AT8_j, u> (raw scaled) ----------------
__global__ __launch_bounds__(256) void k_colp8(const unsigned int* __restrict__ AT,
                                               const float* __restrict__ u,
                                               float* __restrict__ w) {
    const int wv = threadIdx.x >> 6, lane = threadIdx.x & 63;
    const int j = blockIdx.x * 4 + wv;
    const uint2* __restrict__ A2 = reinterpret_cast<const uint2*>(AT);
    const float4* __restrict__ u4 = reinterpret_cast<const float4*>(u);
    float s = 0.f;
#pragma unroll
    for (int p = 0; p < 8; ++p) {
        float f[8];
        dec8(A2[(size_t)j * 512 + p * 64 + lane], f);
        float4 ua = u4[p * 128 + lane];
        float4 ub = u4[p * 128 + 64 + lane];
        s = fmaf(f[0], ua.x, s);
        s = fmaf(f[1], ua.y, s);
        s = fmaf(f[2], ua.z, s);
        s = fmaf(f[3], ua.w, s);
        s = fmaf(f[4], ub.x, s);
        s = fmaf(f[5], ub.y, s);
        s = fmaf(f[6], ub.z, s);
        s = fmaf(f[7], ub.w, s);
    }
#pragma unroll
    for (int o = 1; o < 64; o <<= 1) s += __shfl_xor(s, o, 64);
    if (lane == 0) w[j] = s;
}

// ---------------- power iter: partial[ch][i] = sum_{j in ch} AT8[j][i] * (zv[j]/scalars[0]) ----
__global__ __launch_bounds__(256) void k_azp8s(const unsigned int* __restrict__ AT,
                                               const float* __restrict__ zv,
                                               float* __restrict__ partial,
                                               const float* __restrict__ scalars) {
    const int ch = blockIdx.y;
    const int j0 = ch * AZ_J;
    const int p = blockIdx.x * 256 + threadIdx.x;   // phys uint2 idx 0..511
    __shared__ float sz[AZ_J];
    if (threadIdx.x < AZ_J) sz[threadIdx.x] = zv[j0 + threadIdx.x] / scalars[0];
    __syncthreads();
    const uint2* __restrict__ A2 = reinterpret_cast<const uint2*>(AT);
    float acc[8];
#pragma unroll
    for (int e = 0; e < 8; ++e) acc[e] = 0.f;
    for (int jj = 0; jj < AZ_J; ++jj) {
        float f[8];
        dec8(A2[(size_t)(j0 + jj) * 512 + p], f);
        float zj = sz[jj];
#pragma unroll
        for (int e = 0; e < 8; ++e) acc[e] = fmaf(f[e], zj, acc[e]);
    }
    const int ibase = (p >> 6) * 512 + (p & 63) * 4;
    float* __restrict__ P = partial + (size_t)ch * NPAD;
    *reinterpret_cast<float4*>(&P[ibase])       = make_float4(acc[0], acc[1], acc[2], acc[3]);
    *reinterpret_cast<float4*>(&P[ibase + 256]) = make_float4(acc[4], acc[5], acc[6], acc[7]);
}

// ---------------- final polish: fp16 column dot + x-update ----------------
template <int MODE>
__global__ __launch_bounds__(256) void k_col(const half_t* __restrict__ AT,
                                             const float* __restrict__ u,
                                             const float* __restrict__ c,
                                             const float* __restrict__ b,
                                             float* __restrict__ x,
                                             float* __restrict__ z,
                                             float* __restrict__ w,
                                             const float* __restrict__ scalars) {
    const int wv   = threadIdx.x >> 6;
    const int lane = threadIdx.x & 63;
    const int j = blockIdx.x * 4 + wv;
    const half8* __restrict__ row = reinterpret_cast<const half8*>(AT + (size_t)j * NPAD);
    const float4* __restrict__ u4 = reinterpret_cast<const float4*>(u);
    float s = 0.f;
#pragma unroll
    for (int it = 0; it < NPAD / 8 / 64; ++it) {
        int k = it * 64 + lane;
        half8 a = row[k];
        float4 ua = u4[2 * k];
        float4 ub = u4[2 * k + 1];
        s = fmaf((float)a[0], ua.x, s);
        s = fmaf((float)a[1], ua.y, s);
        s = fmaf((float)a[2], ua.z, s);
        s = fmaf((float)a[3], ua.w, s);
        s = fmaf((float)a[4], ub.x, s);
        s = fmaf((float)a[5], ub.y, s);
        s = fmaf((float)a[6], ub.z, s);
        s = fmaf((float)a[7], ub.w, s);
    }
#pragma unroll
    for (int o = 1; o < 64; o <<= 1) s += __shfl_xor(s, o, 64);
    if (lane == 0) {
        if (MODE == 0) {
            w[j] = s;
        } else {
            float tau = scalars[1];
            float xo = x[j];
            float xn = xo - tau * (c[j] + s);
            xn = fminf(fmaxf(xn, 0.f), b[j]);
            x[j] = xn;
            z[j] = 2.f * xn - xo;
        }
    }
}

// ================= fp32 fallback kernels (round-1 verified) =================
__global__ __launch_bounds__(256) void k_at_partial(const float* __restrict__ A,
                                                    const float* __restrict__ u,
                                                    float* __restrict__ partial) {
    const int j4 = blockIdx.x * 256 + threadIdx.x;
    const int r0 = blockIdx.y * ROWS_PER_CHUNK;
    const int r1 = min(r0 + ROWS_PER_CHUNK, N_ROWS);
    __shared__ float su[ROWS_PER_CHUNK];
    if (threadIdx.x < (unsigned)(r1 - r0)) su[threadIdx.x] = u[r0 + threadIdx.x];
    __syncthreads();
    const float4* __restrict__ A4 = reinterpret_cast<const float4*>(A);
    float4 acc = make_float4(0.f, 0.f, 0.f, 0.f);
    for (int i = r0; i < r1; ++i) {
        const float ui = su[i - r0];
        float4 a = A4[(size_t)i * M4 + j4];
        acc.x = fmaf(a.x, ui, acc.x);
        acc.y = fmaf(a.y, ui, acc.y);
        acc.z = fmaf(a.z, ui, acc.z);
        acc.w = fmaf(a.w, ui, acc.w);
    }
    reinterpret_cast<float4*>(partial)[(size_t)blockIdx.y * M4 + j4] = acc;
}

__global__ __launch_bounds__(256) void k_reduce_w(const float* __restrict__ partial,
                                                  float* __restrict__ w) {
    int j = blockIdx.x * 256 + threadIdx.x;
    float s = 0.f;
    for (int p = 0; p < P_CHUNKS; ++p) s += partial[(size_t)p * M_COLS + j];
    w[j] = s;
}

__global__ __launch_bounds__(256) void k_x_update(const float* __restrict__ partial,
                                                  const float* __restrict__ c,
                                                  const float* __restrict__ b,
                                                  float* __restrict__ x,
                                                  float* __restrict__ z,
                                                  const float* __restrict__ scalars) {
    int j = blockIdx.x * 256 + threadIdx.x;
    const float tau = scalars[1];
    float s = 0.f;
    for (int p = 0; p < P_CHUNKS; ++p) s += partial[(size_t)p * M_COLS + j];
    float xo = x[j];
    float xn = xo - tau * (c[j] + s);
    xn = fminf(fmaxf(xn, 0.f), b[j]);
    x[j] = xn;
    z[j] = 2.f * xn - xo;
}

template <int MODE>
__global__ __launch_bounds__(256) void k_row_dot(const float* __restrict__ A,
                                                 const float* __restrict__ vec,
                                                 float* __restrict__ out,
                                                 const float* __restrict__ scalars) {
    const int i = blockIdx.x;
    const float4* __restrict__ row = reinterpret_cast<const float4*>(A + (size_t)i * M_COLS);
    const float4* __restrict__ v4  = reinterpret_cast<const float4*>(vec);
    float s = 0.f;
    for (int k = threadIdx.x; k < M4; k += 256) {
        float4 a = row[k];
        float4 v = v4[k];
        s = fmaf(a.x, v.x, s);
        s = fmaf(a.y, v.y, s);
        s = fmaf(a.z, v.z, s);
        s = fmaf(a.w, v.w, s);
    }
    for (int o = 32; o > 0; o >>= 1) s += __shfl_down(s, o, 64);
    __shared__ float sm[4];
    if ((threadIdx.x & 63) == 0) sm[threadIdx.x >> 6] = s;
    __syncthreads();
    if (threadIdx.x == 0) {
        float t = sm[0] + sm[1] + sm[2] + sm[3];
        if (MODE == 0) out[i] = t;
        else           out[i] += scalars[1] * t;
    }
}

// ---------------- norms ----------------
// MODE 0: scalars[0] = ||w||
// MODE 1: fp8-scaled: w = 4096*A^T A v -> tau = 57.6/sqrt(||w||); scalars[2]=tau/64
// MODE 2: true-scale: tau = 0.9/sqrt(||w||)
template <int MODE>
__global__ __launch_bounds__(1024) void k_norm(const float* __restrict__ w,
                                               float* __restrict__ scalars) {
    const float4* __restrict__ w4 = reinterpret_cast<const float4*>(w);
    float s = 0.f;
    for (int k = threadIdx.x; k < M4; k += 1024) {
        float4 a = w4[k];
        s = fmaf(a.x, a.x, s);
        s = fmaf(a.y, a.y, s);
        s = fmaf(a.z, a.z, s);
        s = fmaf(a.w, a.w, s);
    }
    for (int o = 32; o > 0; o >>= 1) s += __shfl_down(s, o, 64);
    __shared__ float sm[16];
    if ((threadIdx.x & 63) == 0) sm[threadIdx.x >> 6] = s;
    __syncthreads();
    if (threadIdx.x == 0) {
        float t = 0.f;
        for (int q = 0; q < 16; ++q) t += sm[q];
        float nrm = sqrtf(t);               // ||w||
        if (MODE == 0) scalars[0] = nrm;
        else if (MODE == 1) {
            float tau = 57.6f / sqrtf(nrm); // 0.9*64/sqrt(||w||_meas)
            scalars[1] = tau;
            scalars[2] = tau * 0.015625f;
        } else {
            scalars[1] = 0.9f / sqrtf(nrm);
        }
    }
}

__global__ __launch_bounds__(256) void k_scale(const float* __restrict__ w,
                                               float* __restrict__ v,
                                               const float* __restrict__ scalars) {
    int j = blockIdx.x * 256 + threadIdx.x;
    v[j] = w[j] / scalars[0];
}

__global__ __launch_bounds__(1024) void k_obj(const float* __restrict__ x,
                                              const float* __restrict__ c,
                                              float* __restrict__ out) {
    float s = 0.f;
    for (int k = threadIdx.x; k < M_COLS; k += 1024) s = fmaf(x[k], -c[k], s);
    for (int o = 32; o > 0; o >>= 1) s += __shfl_down(s, o, 64);
    __shared__ float sm[16];
    if ((threadIdx.x & 63) == 0) sm[threadIdx.x >> 6] = s;
    __syncthreads();
    if (threadIdx.x == 0) {
        float t = 0.f;
        for (int q = 0; q < 16; ++q) t += sm[q];
        out[0] = t;
    }
}

extern "C" void kernel_launch(void* const* d_in, const int* in_sizes, int n_in,
                              void* d_out, int out_size, void* d_ws, size_t ws_size,
                              hipStream_t stream) {
    const float* A = (const float*)d_in[0];
    const float* b = (const float*)d_in[1];
    const float* c = (const float*)d_in[2];
    float* out = (float*)d_out;

    float* ws = (float*)d_ws;
    float* x       = ws;                        // M
    float* z       = x + M_COLS;                // M
    float* v       = z + M_COLS;                // M
    float* w       = v + M_COLS;                // M
    float* y       = w + M_COLS;                // NPAD
    float* t       = y + NPAD;                  // NPAD
    float* scalars = t + NPAD;                  // 16
    float* partial = scalars + 16;              // 8 MB region (fp32 power / fp16 PDHG)

    size_t partial_floats = (size_t)2 * 1024 * 1024;
    size_t base = (size_t)(partial - ws) * 4 + partial_floats * 4;
    size_t a8_off = (base + 255) & ~(size_t)255;
    unsigned int* AT8 = (unsigned int*)((char*)d_ws + a8_off);
    size_t a8_bytes = (size_t)M_COLS * NPAD;                  // 64 MB
    size_t a16_off = (a8_off + a8_bytes + 255) & ~(size_t)255;
    half_t* AT16 = (half_t*)((char*)d_ws + a16_off);
    size_t a16_bytes = (size_t)M_COLS * NPAD * sizeof(half_t); // 134.2 MB
    size_t need_full = a16_off + a16_bytes;                    // ~207 MB
    size_t need_fp32 = (size_t)(partial - ws) * 4 + (size_t)P_CHUNKS * M_COLS * 4;

    dim3 b256(256);
    dim3 b512(512);
    dim3 gM(M_COLS / 256);            // 64
    dim3 gCol(M_COLS / 4);            // 4096
    dim3 gFused(FBLOCKS);             // 256 blocks x 512 threads
    dim3 gAz(NPAD / 8 / 256, AZ_CH);  // (2, 256)
    dim3 gMerge(NPAD / 16);           // 256
    dim3 gRowA(N_ROWS);
    dim3 gTr(NPAD / 64, M_COLS / 64); // (64, 256)

    k_init<<<gM, b256, 0, stream>>>(x, v, y, t, scalars);

    if (ws_size >= need_full) {
        // ======== fp8 path: 299 two-launch iters + fp16 polish ========
        k_transpose_both<<<gTr, b256, 0, stream>>>(A, AT8, AT16);

        // power iteration with scaled staging (no explicit normalize kernel)
        k_azp8s<<<gAz, b256, 0, stream>>>(AT8, v, partial, scalars);   // v/1
        k_merge0<AZ_CH><<<gMerge, b256, 0, stream>>>(partial, t);
        k_colp8<<<gCol, b256, 0, stream>>>(AT8, t, w);
        k_norm<0><<<1, 1024, 0, stream>>>(w, scalars);
        for (int it = 1; it < POWER_ITERS; ++it) {
            k_azp8s<<<gAz, b256, 0, stream>>>(AT8, w, partial, scalars); // w/||w||
            k_merge0<AZ_CH><<<gMerge, b256, 0, stream>>>(partial, t);
            k_colp8<<<gCol, b256, 0, stream>>>(AT8, t, w);
            k_norm<0><<<1, 1024, 0, stream>>>(w, scalars);
        }
        k_azp8s<<<gAz, b256, 0, stream>>>(AT8, w, partial, scalars);
        k_merge0<AZ_CH><<<gMerge, b256, 0, stream>>>(partial, t);
        k_colp8<<<gCol, b256, 0, stream>>>(AT8, t, w);
        k_norm<1><<<1, 1024, 0, stream>>>(w, scalars);                 // tau, tau/64

        for (int it = 0; it < PDHG_ITERS - 1; ++it) {
            k_fused8<<<gFused, b512, 0, stream>>>(AT8, y, c, b, x,
                                                  (half_t*)partial, scalars);
            k_merge_h<FBLOCKS><<<gMerge, b256, 0, stream>>>((half_t*)partial, y, scalars);
        }
        // final x-step (its y-half is unused by the output) in fp16
        k_col<1><<<gCol, b256, 0, stream>>>(AT16, y, c, b, x, z, w, scalars);
    } else if (ws_size >= need_fp32) {
        // ======== fp32 fallback (full 300, 20 power iters) ========
        dim3 gAt(M4 / 256, P_CHUNKS);
        for (int it = 0; it < 20; ++it) {
            k_row_dot<0><<<gRowA, b256, 0, stream>>>(A, v, t, scalars);
            k_at_partial<<<gAt, b256, 0, stream>>>(A, t, partial);
            k_reduce_w<<<gM, b256, 0, stream>>>(partial, w);
            k_norm<0><<<1, 1024, 0, stream>>>(w, scalars);
            k_scale<<<gM, b256, 0, stream>>>(w, v, scalars);
        }
        k_row_dot<0><<<gRowA, b256, 0, stream>>>(A, v, t, scalars);
        k_at_partial<<<gAt, b256, 0, stream>>>(A, t, partial);
        k_reduce_w<<<gM, b256, 0, stream>>>(partial, w);
        k_norm<2><<<1, 1024, 0, stream>>>(w, scalars);
        for (int it = 0; it < PDHG_ITERS; ++it) {
            k_at_partial<<<gAt, b256, 0, stream>>>(A, y, partial);
            k_x_update<<<gM, b256, 0, stream>>>(partial, c, b, x, z, scalars);
            k_row_dot<1><<<gRowA, b256, 0, stream>>>(A, z, y, scalars);
        }
    }

    k_obj<<<1, 1024, 0, stream>>>(x, c, out);
}